// Round 5
// baseline (412.935 us; speedup 1.0000x reference)
//
#include <hip/hip_runtime.h>
#include <cstdint>
#include <math.h>

namespace {

constexpr int QBLOCK = 64;
// jax: q = 0.95f * 63.0f -> f32 59.849998474121094
// high_weight = q - 59 = 0.84999847412109375 (exact), low_weight = 60 - q (exact)
constexpr float W59 = 0.15000152587890625f;  // weight for sorted[59] (5th largest)
constexpr float W60 = 0.84999847412109375f;  // weight for sorted[60] (4th largest)

__global__ void init_mm(unsigned* mm) {
  if (threadIdx.x == 0) {
    mm[0] = 0x7F800000u;  // +inf bits -> min identity
    mm[1] = 0u;           // 0.0 bits  -> max identity (scales > 0)
  }
}

// Branchless insert of v into descending top-5 list t[0]>=...>=t[4].
__device__ inline void ins5(float (&t)[5], float v) {
#pragma unroll
  for (int k = 0; k < 4; ++k) {
    float m = fmaxf(t[k], v);
    v = fminf(t[k], v);
    t[k] = m;
  }
  t[4] = fmaxf(t[4], v);
}

// 4 lanes per 64-element quant block, interleaved so loads coalesce:
// thread (b, sub) loads x4[b*16 + sub + 4j], j=0..3  (sub = tid&3).
__global__ __launch_bounds__(256) void scales_k(const float4* __restrict__ x4,
                                                float* __restrict__ scales,
                                                unsigned* __restrict__ mm,
                                                int nblocks) {
  const int tid = blockIdx.x * 256 + threadIdx.x;
  const int b = tid >> 2;
  float lmin = __uint_as_float(0x7F800000u);  // +inf
  float lmax = 0.0f;
  if (b < nblocks) {
    const float4* p = x4 + ((size_t)(tid >> 2) << 4) + (tid & 3);
    // 4 independent coalesced loads (named scalars -> no spillable array).
    float4 v0 = p[0];
    float4 v1 = p[4];
    float4 v2 = p[8];
    float4 v3 = p[12];
    // Two interleaved top-5 lists (ILP); |x| >= 0 > -1 sentinel.
    float ta[5] = {-1.f, -1.f, -1.f, -1.f, -1.f};
    float tb[5] = {-1.f, -1.f, -1.f, -1.f, -1.f};
    ins5(ta, fabsf(v0.x));
    ins5(tb, fabsf(v2.x));
    ins5(ta, fabsf(v0.y));
    ins5(tb, fabsf(v2.y));
    ins5(ta, fabsf(v0.z));
    ins5(tb, fabsf(v2.z));
    ins5(ta, fabsf(v0.w));
    ins5(tb, fabsf(v2.w));
    ins5(ta, fabsf(v1.x));
    ins5(tb, fabsf(v3.x));
    ins5(ta, fabsf(v1.y));
    ins5(tb, fabsf(v3.y));
    ins5(ta, fabsf(v1.z));
    ins5(tb, fabsf(v3.z));
    ins5(ta, fabsf(v1.w));
    ins5(tb, fabsf(v3.w));
#pragma unroll
    for (int k = 0; k < 5; ++k) ins5(ta, tb[k]);  // top-5 of my 16
    // Butterfly merge across the 4 lanes of this block (xor 1, then xor 2).
    float pb[5];
#pragma unroll
    for (int k = 0; k < 5; ++k) pb[k] = __shfl_xor(ta[k], 1);
#pragma unroll
    for (int k = 0; k < 5; ++k) ins5(ta, pb[k]);
#pragma unroll
    for (int k = 0; k < 5; ++k) pb[k] = __shfl_xor(ta[k], 2);
#pragma unroll
    for (int k = 0; k < 5; ++k) ins5(ta, pb[k]);
    // All 4 lanes now hold the block's exact top-5.
    // sorted[60] = 4th largest = ta[3]; sorted[59] = 5th largest = ta[4]
    // bit-exact jax quantile: add(mul(lo,w_lo), mul(hi,w_hi)) in f32, no FMA
    float sc = __fadd_rn(__fmul_rn(ta[4], W59), __fmul_rn(ta[3], W60));
    sc = fmaxf(sc, 1e-8f);  // jnp.clip(scales, 1e-8)
    if ((tid & 3) == 0) scales[b] = sc;
    lmin = sc;
    lmax = sc;
  }
  // Wave-level min/max reduction, one atomic pair per wave.
#pragma unroll
  for (int off = 32; off; off >>= 1) {
    lmin = fminf(lmin, __shfl_xor(lmin, off));
    lmax = fmaxf(lmax, __shfl_xor(lmax, off));
  }
  if ((threadIdx.x & 63) == 0) {
    // positive floats: uint bit order == float order
    atomicMin(mm + 0, __float_as_uint(lmin));
    atomicMax(mm + 1, __float_as_uint(lmax));
  }
}

__global__ __launch_bounds__(256) void deq_k(const float4* __restrict__ x4,
                                             const float* __restrict__ scales,
                                             const unsigned* __restrict__ mm,
                                             float4* __restrict__ o4, int n4) {
  const float smin = __uint_as_float(mm[0]);
  const float smax = __uint_as_float(mm[1]);
  const bool nd = smax > smin;
  const float ss = nd ? __fdiv_rn(__fsub_rn(smax, smin), 255.0f) : 1.0f;
  int i = blockIdx.x * blockDim.x + threadIdx.x;
  const int stride = gridDim.x * blockDim.x;
  for (; i < n4; i += stride) {
    float4 v = x4[i];
    float s = scales[i >> 4];  // element 4*i / 64
    float dq = 0.0f;
    if (nd) {
      float q = rintf(__fdiv_rn(__fsub_rn(s, smin), ss));  // jnp.round = RNE
      q = fminf(fmaxf(q, 0.0f), 255.0f);
      dq = __fmul_rn(q, ss);  // q_scales * scale_scale (no s_min added back)
    }
    float xs[4] = {v.x, v.y, v.z, v.w};
    float os[4];
#pragma unroll
    for (int j = 0; j < 4; ++j) {
      float xv = xs[j];
      float xn = __fdiv_rn(xv, s);  // IEEE divide, matches XLA
      float ax = fabsf(xn);
      // nearest FP4 level; argmin first-min tie-break:
      //   negative x: tie -> more-negative level  => count (ax >= midpoint)
      //   positive x: tie -> smaller level        => count (ax >  midpoint)
      int c;
      if (xn < 0.0f)
        c = (int)(ax >= 0.375f) + (int)(ax >= 0.875f) + (int)(ax >= 1.25f) +
            (int)(ax >= 1.75f) + (int)(ax >= 2.5f);
      else
        c = (int)(ax > 0.375f) + (int)(ax > 0.875f) + (int)(ax > 1.25f) +
            (int)(ax > 1.75f) + (int)(ax > 2.5f);
      float mag = (c == 0) ? 0.0f
                : (c == 1) ? 0.75f
                : (c == 2) ? 1.0f
                : (c == 3) ? 1.5f
                : (c == 4) ? 2.0f
                           : 3.0f;
      float lvl = (xn < 0.0f) ? -mag : mag;
      float xq = __fmul_rn(lvl, dq);
      // faithful STE arithmetic: x + (x_q - x)
      os[j] = __fadd_rn(xv, __fsub_rn(xq, xv));
    }
    float4 o;
    o.x = os[0]; o.y = os[1]; o.z = os[2]; o.w = os[3];
    o4[i] = o;
  }
}

}  // namespace

extern "C" void kernel_launch(void* const* d_in, const int* in_sizes, int n_in,
                              void* d_out, int out_size, void* d_ws, size_t ws_size,
                              hipStream_t stream) {
  const float* x = (const float*)d_in[0];
  float* out = (float*)d_out;
  const int n = in_sizes[0];
  const int nblocks = n / QBLOCK;
  unsigned* mm = (unsigned*)d_ws;
  float* scales = (float*)((char*)d_ws + 16);

  hipLaunchKernelGGL(init_mm, dim3(1), dim3(64), 0, stream, mm);
  const long long nthreads = (long long)nblocks * 4;  // 4 lanes per block
  const int wgs = (int)((nthreads + 255) / 256);
  hipLaunchKernelGGL(scales_k, dim3(wgs), dim3(256), 0, stream,
                     (const float4*)x, scales, mm, nblocks);
  const int n4 = n / 4;
  hipLaunchKernelGGL(deq_k, dim3(4096), dim3(256), 0, stream, (const float4*)x,
                     scales, mm, (float4*)out, n4);
}

// Round 6
// 66.190 us; speedup vs baseline: 6.2386x; 6.2386x over previous
//
#include <hip/hip_runtime.h>
#include <cstdint>
#include <math.h>

namespace {

constexpr int QBLOCK = 64;
// jax: q = 0.95f * 63.0f -> f32 59.849998474121094
// high_weight = q - 59 = 0.84999847412109375 (exact), low_weight = 60 - q (exact)
constexpr float W59 = 0.15000152587890625f;  // weight for sorted[59] (5th largest)
constexpr float W60 = 0.84999847412109375f;  // weight for sorted[60] (4th largest)

__global__ void init_mm(unsigned* mm) {
  if (threadIdx.x == 0) {
    mm[0] = 0x7F800000u;  // +inf bits -> min identity
    mm[1] = 0u;           // 0.0 bits  -> max identity (scales > 0)
  }
}

// Branchless insert of v into descending top-5 list t[0]>=...>=t[4].
__device__ inline void ins5(float (&t)[5], float v) {
#pragma unroll
  for (int k = 0; k < 4; ++k) {
    float m = fmaxf(t[k], v);
    v = fminf(t[k], v);
    t[k] = m;
  }
  t[4] = fmaxf(t[4], v);
}

__device__ inline void ins4x(float (&ta)[5], float (&tb)[5], float4 u, float4 w) {
  ins5(ta, fabsf(u.x));
  ins5(tb, fabsf(w.x));
  ins5(ta, fabsf(u.y));
  ins5(tb, fabsf(w.y));
  ins5(ta, fabsf(u.z));
  ins5(tb, fabsf(w.z));
  ins5(ta, fabsf(u.w));
  ins5(tb, fabsf(w.w));
}

// One thread per 64-element quant block (round-4 body). Atomic traffic cut to
// ONE min/max pair per 256-thread workgroup: rounds 1-5 showed kernel time was
// ~12.5 ns x (number of per-wave atomic pairs) -- a serialized same-address
// atomic chain at the L2 home point, hiding everything else under it.
__global__ __launch_bounds__(256) void scales_k(const float4* __restrict__ x4,
                                                float* __restrict__ scales,
                                                unsigned* __restrict__ mm,
                                                int nblocks) {
  __shared__ float smn[256];
  __shared__ float smx[256];
  const int t = threadIdx.x;
  const int b = blockIdx.x * 256 + t;
  float sc_min = __uint_as_float(0x7F800000u);  // +inf
  float sc_max = 0.0f;
  if (b < nblocks) {
    const float4* p = x4 + (size_t)b * (QBLOCK / 4);
    float4 a0 = p[0], a1 = p[1], a2 = p[2], a3 = p[3];
    float4 a4 = p[4], a5 = p[5], a6 = p[6], a7 = p[7];
    float4 b0 = p[8], b1 = p[9], b2 = p[10], b3 = p[11];
    float4 b4 = p[12], b5 = p[13], b6 = p[14], b7 = p[15];
    // Two interleaved top-5 lists for ILP; |x| >= 0 > -1 sentinel.
    float ta[5] = {-1.f, -1.f, -1.f, -1.f, -1.f};
    float tb[5] = {-1.f, -1.f, -1.f, -1.f, -1.f};
    ins4x(ta, tb, a0, a1);
    ins4x(ta, tb, a2, a3);
    ins4x(ta, tb, a4, a5);
    ins4x(ta, tb, a6, a7);
    ins4x(ta, tb, b0, b1);
    ins4x(ta, tb, b2, b3);
    ins4x(ta, tb, b4, b5);
    ins4x(ta, tb, b6, b7);
#pragma unroll
    for (int k = 0; k < 5; ++k) ins5(ta, tb[k]);  // top-5 of the 64
    // sorted[60] = 4th largest = ta[3]; sorted[59] = 5th largest = ta[4]
    // bit-exact jax quantile: add(mul(lo,w_lo), mul(hi,w_hi)) in f32, no FMA
    float sc = __fadd_rn(__fmul_rn(ta[4], W59), __fmul_rn(ta[3], W60));
    sc = fmaxf(sc, 1e-8f);  // jnp.clip(scales, 1e-8)
    scales[b] = sc;
    sc_min = sc;
    sc_max = sc;
  }
  smn[t] = sc_min;
  smx[t] = sc_max;
  __syncthreads();
  if (t < 64) {
    float mn = fminf(fminf(smn[t], smn[t + 64]), fminf(smn[t + 128], smn[t + 192]));
    float mx = fmaxf(fmaxf(smx[t], smx[t + 64]), fmaxf(smx[t + 128], smx[t + 192]));
#pragma unroll
    for (int off = 32; off; off >>= 1) {
      mn = fminf(mn, __shfl_xor(mn, off));
      mx = fmaxf(mx, __shfl_xor(mx, off));
    }
    if (t == 0) {
      // positive floats: uint bit order == float order
      atomicMin(mm + 0, __float_as_uint(mn));
      atomicMax(mm + 1, __float_as_uint(mx));
    }
  }
}

__global__ __launch_bounds__(256) void deq_k(const float4* __restrict__ x4,
                                             const float* __restrict__ scales,
                                             const unsigned* __restrict__ mm,
                                             float4* __restrict__ o4, int n4) {
  const float smin = __uint_as_float(mm[0]);
  const float smax = __uint_as_float(mm[1]);
  const bool nd = smax > smin;
  const float ss = nd ? __fdiv_rn(__fsub_rn(smax, smin), 255.0f) : 1.0f;
  int i = blockIdx.x * blockDim.x + threadIdx.x;
  const int stride = gridDim.x * blockDim.x;
  for (; i < n4; i += stride) {
    float4 v = x4[i];
    float s = scales[i >> 4];  // element 4*i / 64
    float dq = 0.0f;
    if (nd) {
      float q = rintf(__fdiv_rn(__fsub_rn(s, smin), ss));  // jnp.round = RNE
      q = fminf(fmaxf(q, 0.0f), 255.0f);
      dq = __fmul_rn(q, ss);  // q_scales * scale_scale (no s_min added back)
    }
    float xs[4] = {v.x, v.y, v.z, v.w};
    float os[4];
#pragma unroll
    for (int j = 0; j < 4; ++j) {
      float xv = xs[j];
      float xn = __fdiv_rn(xv, s);  // IEEE divide, matches XLA
      float ax = fabsf(xn);
      // nearest FP4 level; argmin first-min tie-break:
      //   negative x: tie -> more-negative level  => count (ax >= midpoint)
      //   positive x: tie -> smaller level        => count (ax >  midpoint)
      int c;
      if (xn < 0.0f)
        c = (int)(ax >= 0.375f) + (int)(ax >= 0.875f) + (int)(ax >= 1.25f) +
            (int)(ax >= 1.75f) + (int)(ax >= 2.5f);
      else
        c = (int)(ax > 0.375f) + (int)(ax > 0.875f) + (int)(ax > 1.25f) +
            (int)(ax > 1.75f) + (int)(ax > 2.5f);
      float mag = (c == 0) ? 0.0f
                : (c == 1) ? 0.75f
                : (c == 2) ? 1.0f
                : (c == 3) ? 1.5f
                : (c == 4) ? 2.0f
                           : 3.0f;
      float lvl = (xn < 0.0f) ? -mag : mag;
      float xq = __fmul_rn(lvl, dq);
      // faithful STE arithmetic: x + (x_q - x)
      os[j] = __fadd_rn(xv, __fsub_rn(xq, xv));
    }
    float4 o;
    o.x = os[0]; o.y = os[1]; o.z = os[2]; o.w = os[3];
    o4[i] = o;
  }
}

}  // namespace

extern "C" void kernel_launch(void* const* d_in, const int* in_sizes, int n_in,
                              void* d_out, int out_size, void* d_ws, size_t ws_size,
                              hipStream_t stream) {
  const float* x = (const float*)d_in[0];
  float* out = (float*)d_out;
  const int n = in_sizes[0];
  const int nblocks = n / QBLOCK;
  unsigned* mm = (unsigned*)d_ws;
  float* scales = (float*)((char*)d_ws + 16);

  hipLaunchKernelGGL(init_mm, dim3(1), dim3(64), 0, stream, mm);
  const int wgs = (nblocks + 255) / 256;  // 1024 WGs -> 1024 atomic pairs
  hipLaunchKernelGGL(scales_k, dim3(wgs), dim3(256), 0, stream,
                     (const float4*)x, scales, mm, nblocks);
  const int n4 = n / 4;
  hipLaunchKernelGGL(deq_k, dim3(4096), dim3(256), 0, stream, (const float4*)x,
                     scales, mm, (float4*)out, n4);
}

// Round 8
// 46.164 us; speedup vs baseline: 8.9449x; 1.4338x over previous
//
#include <hip/hip_runtime.h>
#include <cstdint>
#include <math.h>

namespace {

constexpr int QBLOCK = 64;
// jax: q = 0.95f * 63.0f -> f32 59.849998474121094
// high_weight = q - 59 = 0.84999847412109375 (exact), low_weight = 60 - q (exact)
constexpr float W59 = 0.15000152587890625f;  // weight for sorted[59] (5th largest)
constexpr float W60 = 0.84999847412109375f;  // weight for sorted[60] (4th largest)

// Branchless insert of v into descending top-5 list t[0]>=...>=t[4].
__device__ inline void ins5(float (&t)[5], float v) {
#pragma unroll
  for (int k = 0; k < 4; ++k) {
    float m = fmaxf(t[k], v);
    v = fminf(t[k], v);
    t[k] = m;
  }
  t[4] = fmaxf(t[4], v);
}

__device__ inline void ins4x(float (&ta)[5], float (&tb)[5], float4 u, float4 w) {
  ins5(ta, fabsf(u.x));
  ins5(tb, fabsf(w.x));
  ins5(ta, fabsf(u.y));
  ins5(tb, fabsf(w.y));
  ins5(ta, fabsf(u.z));
  ins5(tb, fabsf(w.z));
  ins5(ta, fabsf(u.w));
  ins5(tb, fabsf(w.w));
}

// One thread per 64-element quant block. NO atomics anywhere: WG min/max goes
// to part[wg] via plain store (rounds 1-6: same-address atomic chains at
// ~12.5 ns/pair dominated everything).
__global__ __launch_bounds__(256) void scales_k(const float4* __restrict__ x4,
                                                float* __restrict__ scales,
                                                float2* __restrict__ part,
                                                int nblocks) {
  __shared__ float smn[256];
  __shared__ float smx[256];
  const int t = threadIdx.x;
  const int b = blockIdx.x * 256 + t;
  float sc_min = __uint_as_float(0x7F800000u);  // +inf
  float sc_max = 0.0f;
  if (b < nblocks) {
    const float4* p = x4 + (size_t)b * (QBLOCK / 4);
    float4 a0 = p[0], a1 = p[1], a2 = p[2], a3 = p[3];
    float4 a4 = p[4], a5 = p[5], a6 = p[6], a7 = p[7];
    float4 b0 = p[8], b1 = p[9], b2 = p[10], b3 = p[11];
    float4 b4 = p[12], b5 = p[13], b6 = p[14], b7 = p[15];
    // Two interleaved top-5 lists for ILP; |x| >= 0 > -1 sentinel.
    float ta[5] = {-1.f, -1.f, -1.f, -1.f, -1.f};
    float tb[5] = {-1.f, -1.f, -1.f, -1.f, -1.f};
    ins4x(ta, tb, a0, a1);
    ins4x(ta, tb, a2, a3);
    ins4x(ta, tb, a4, a5);
    ins4x(ta, tb, a6, a7);
    ins4x(ta, tb, b0, b1);
    ins4x(ta, tb, b2, b3);
    ins4x(ta, tb, b4, b5);
    ins4x(ta, tb, b6, b7);
#pragma unroll
    for (int k = 0; k < 5; ++k) ins5(ta, tb[k]);  // top-5 of the 64
    // sorted[60] = 4th largest = ta[3]; sorted[59] = 5th largest = ta[4]
    // bit-exact jax quantile: add(mul(lo,w_lo), mul(hi,w_hi)) in f32, no FMA
    float sc = __fadd_rn(__fmul_rn(ta[4], W59), __fmul_rn(ta[3], W60));
    sc = fmaxf(sc, 1e-8f);  // jnp.clip(scales, 1e-8)
    scales[b] = sc;
    sc_min = sc;
    sc_max = sc;
  }
  smn[t] = sc_min;
  smx[t] = sc_max;
  __syncthreads();
  if (t < 64) {
    float mn = fminf(fminf(smn[t], smn[t + 64]), fminf(smn[t + 128], smn[t + 192]));
    float mx = fmaxf(fmaxf(smx[t], smx[t + 64]), fmaxf(smx[t + 128], smx[t + 192]));
#pragma unroll
    for (int off = 32; off; off >>= 1) {
      mn = fminf(mn, __shfl_xor(mn, off));
      mx = fmaxf(mx, __shfl_xor(mx, off));
    }
    if (t == 0) part[blockIdx.x] = make_float2(mn, mx);
  }
}

// Each WG re-reduces the nwg partials itself (8 KB, L2-resident), then
// grid-strides the dequant. Kernel boundary orders part[]/scales[] writes.
__global__ __launch_bounds__(256) void deq_k(const float4* __restrict__ x4,
                                             const float* __restrict__ scales,
                                             const float2* __restrict__ part,
                                             float4* __restrict__ o4, int n4,
                                             int nwg) {
  __shared__ float smn[256];
  __shared__ float smx[256];
  __shared__ float bc[2];
  const int t = threadIdx.x;
  float mn = __uint_as_float(0x7F800000u);
  float mx = 0.0f;
  for (int i = t; i < nwg; i += 256) {
    float2 pr = part[i];
    mn = fminf(mn, pr.x);
    mx = fmaxf(mx, pr.y);
  }
  smn[t] = mn;
  smx[t] = mx;
  __syncthreads();
  if (t < 64) {
    float mn2 = fminf(fminf(smn[t], smn[t + 64]), fminf(smn[t + 128], smn[t + 192]));
    float mx2 = fmaxf(fmaxf(smx[t], smx[t + 64]), fmaxf(smx[t + 128], smx[t + 192]));
#pragma unroll
    for (int off = 32; off; off >>= 1) {
      mn2 = fminf(mn2, __shfl_xor(mn2, off));
      mx2 = fmaxf(mx2, __shfl_xor(mx2, off));
    }
    if (t == 0) {
      bc[0] = mn2;
      bc[1] = mx2;
    }
  }
  __syncthreads();
  const float smin = bc[0];
  const float smax = bc[1];
  const bool nd = smax > smin;
  const float ss = nd ? __fdiv_rn(__fsub_rn(smax, smin), 255.0f) : 1.0f;

  int i = blockIdx.x * blockDim.x + t;
  const int stride = gridDim.x * blockDim.x;
  for (; i < n4; i += stride) {
    float4 v = x4[i];
    float s = scales[i >> 4];  // element 4*i / 64
    float dq = 0.0f;
    if (nd) {
      float q = rintf(__fdiv_rn(__fsub_rn(s, smin), ss));  // jnp.round = RNE
      q = fminf(fmaxf(q, 0.0f), 255.0f);
      dq = __fmul_rn(q, ss);  // q_scales * scale_scale (no s_min added back)
    }
    float xs[4] = {v.x, v.y, v.z, v.w};
    float os[4];
#pragma unroll
    for (int j = 0; j < 4; ++j) {
      float xv = xs[j];
      float xn = __fdiv_rn(xv, s);  // IEEE divide, matches XLA
      float ax = fabsf(xn);
      // nearest FP4 level; argmin first-min tie-break:
      //   negative x: tie -> more-negative level  => count (ax >= midpoint)
      //   positive x: tie -> smaller level        => count (ax >  midpoint)
      int c;
      if (xn < 0.0f)
        c = (int)(ax >= 0.375f) + (int)(ax >= 0.875f) + (int)(ax >= 1.25f) +
            (int)(ax >= 1.75f) + (int)(ax >= 2.5f);
      else
        c = (int)(ax > 0.375f) + (int)(ax > 0.875f) + (int)(ax > 1.25f) +
            (int)(ax > 1.75f) + (int)(ax > 2.5f);
      float mag = (c == 0) ? 0.0f
                : (c == 1) ? 0.75f
                : (c == 2) ? 1.0f
                : (c == 3) ? 1.5f
                : (c == 4) ? 2.0f
                           : 3.0f;
      float lvl = (xn < 0.0f) ? -mag : mag;
      float xq = __fmul_rn(lvl, dq);
      // faithful STE arithmetic: x + (x_q - x)
      os[j] = __fadd_rn(xv, __fsub_rn(xq, xv));
    }
    float4 o;
    o.x = os[0]; o.y = os[1]; o.z = os[2]; o.w = os[3];
    o4[i] = o;
  }
}

}  // namespace

extern "C" void kernel_launch(void* const* d_in, const int* in_sizes, int n_in,
                              void* d_out, int out_size, void* d_ws, size_t ws_size,
                              hipStream_t stream) {
  const float* x = (const float*)d_in[0];
  float* out = (float*)d_out;
  const int n = in_sizes[0];
  const int nblocks = n / QBLOCK;
  float* scales = (float*)d_ws;
  const int nwg = (nblocks + 255) / 256;  // 1024 for 2048x8192
  float2* part = (float2*)((char*)d_ws + (size_t)nblocks * sizeof(float));

  hipLaunchKernelGGL(scales_k, dim3(nwg), dim3(256), 0, stream,
                     (const float4*)x, scales, part, nblocks);
  const int n4 = n / 4;
  hipLaunchKernelGGL(deq_k, dim3(4096), dim3(256), 0, stream, (const float4*)x,
                     scales, part, (float4*)out, n4, nwg);
}